// Round 10
// baseline (251.769 us; speedup 1.0000x reference)
//
#include <hip/hip_runtime.h>

#define NF 256
#define H_ 8
#define M_ 32768

typedef _Float16 f16;
typedef __fp16 fp16v2 __attribute__((ext_vector_type(2)));
typedef _Float16 f16x8 __attribute__((ext_vector_type(8)));
typedef float f32x4 __attribute__((ext_vector_type(4)));
typedef unsigned short u16x8 __attribute__((ext_vector_type(8)));
typedef unsigned int u32x2 __attribute__((ext_vector_type(2)));
typedef unsigned int u32x4 __attribute__((ext_vector_type(4)));

#define GLOAD16(src, dst) \
  __builtin_amdgcn_global_load_lds((const __attribute__((address_space(1))) void*)(src), \
                                   (__attribute__((address_space(3))) void*)(dst), 16, 0, 0)

#define LDS_FENCE() do { asm volatile("s_waitcnt lgkmcnt(0)" ::: "memory"); \
                         __builtin_amdgcn_sched_barrier(0); } while (0)
#define SBAR() asm volatile("s_barrier" ::: "memory")

// ---------------- 256^2 8-phase GEMM core (unchanged from R5) ----------------

__device__ __forceinline__ void stageHT(const f16* __restrict__ g, int r0, int k0,
                                        f16* ldst, int wave, int lane) {
    const int key = lane >> 3;
    const int colsw = k0 + (((lane & 7) ^ key) << 3);
#pragma unroll
    for (int i = 0; i < 2; ++i) {
        int r = i * 64 + wave * 8 + key;
        GLOAD16(g + (size_t)(r0 + r) * 512 + colsw, ldst + (i * 64 + wave * 8) * 64);
    }
}

__device__ __forceinline__ void gemm256_core(const f16* __restrict__ A, const f16* __restrict__ W,
                                             int m0, int n0, f16* lds,
                                             f32x4 (&acc)[8][4], int wave, int lane) {
    const int wr = wave & 1, wc = wave >> 1;
    const int l15 = lane & 15, l4 = lane >> 4;
    stageHT(W, n0,        0, lds + 16384, wave, lane);
    stageHT(W, n0 + 128,  0, lds + 24576, wave, lane);
    stageHT(A, m0,        0, lds,         wave, lane);
    stageHT(A, m0 + 128,  0, lds + 8192,  wave, lane);
    stageHT(W, n0,       64, lds + 32768 + 16384, wave, lane);
    stageHT(W, n0 + 128, 64, lds + 32768 + 24576, wave, lane);
    asm volatile("s_waitcnt vmcnt(4)" ::: "memory");
    SBAR();
#pragma unroll
    for (int t = 0; t < 8; ++t) {
        f16* bufA = lds + (t & 1) * 32768;
        f16* bufB = bufA + 16384;
        f16* nA   = lds + ((t & 1) ^ 1) * 32768;
        f16x8 bfr[4][2];
#pragma unroll
        for (int j = 0; j < 4; ++j)
#pragma unroll
            for (int kk = 0; kk < 2; ++kk) {
                int rb = wc * 64 + j * 16 + l15;
                bfr[j][kk] = *reinterpret_cast<const f16x8*>(
                    bufB + rb * 64 + ((((kk << 2) + l4) ^ (rb & 7)) << 3));
            }
#pragma unroll
        for (int q = 0; q < 4; ++q) {
            f16x8 afr[2][2];
#pragma unroll
            for (int rf = 0; rf < 2; ++rf)
#pragma unroll
                for (int kk = 0; kk < 2; ++kk) {
                    int ra = wr * 128 + q * 32 + rf * 16 + l15;
                    afr[rf][kk] = *reinterpret_cast<const f16x8*>(
                        bufA + ra * 64 + ((((kk << 2) + l4) ^ (ra & 7)) << 3));
                }
            if (q == 0 && t < 7) stageHT(A, m0,       (t + 1) * 64, nA,          wave, lane);
            if (q == 1 && t < 7) stageHT(A, m0 + 128, (t + 1) * 64, nA + 8192,   wave, lane);
            if (q == 2 && t < 6) stageHT(W, n0,       (t + 2) * 64, bufB,        wave, lane);
            if (q == 3 && t < 6) stageHT(W, n0 + 128, (t + 2) * 64, bufB + 8192, wave, lane);
            SBAR();
            LDS_FENCE();
            __builtin_amdgcn_s_setprio(1);
#pragma unroll
            for (int rf = 0; rf < 2; ++rf)
#pragma unroll
                for (int j = 0; j < 4; ++j)
#pragma unroll
                    for (int kk = 0; kk < 2; ++kk)
                        acc[q * 2 + rf][j] = __builtin_amdgcn_mfma_f32_16x16x32_f16(
                            afr[rf][kk], bfr[j][kk], acc[q * 2 + rf][j], 0, 0, 0);
            __builtin_amdgcn_s_setprio(0);
            if (q < 3) SBAR();
        }
        if (t < 6) { asm volatile("s_waitcnt vmcnt(4)" ::: "memory"); }
        else       { asm volatile("s_waitcnt vmcnt(0)" ::: "memory"); }
        SBAR();
    }
}

// ---------------- conversion / prep ----------------

#define QSCALE 0.1803368801111204f   // (1/8) * log2(e)

__global__ void prep_all(const float* __restrict__ x, f16* __restrict__ xh,
                         const float* __restrict__ Wq, const float* __restrict__ Wk,
                         const float* __restrict__ Wv, const float* __restrict__ Wo,
                         const float* __restrict__ bq, const float* __restrict__ bk,
                         const float* __restrict__ bv, const int* __restrict__ adj,
                         f16* __restrict__ Wh, f16* __restrict__ Woh,
                         float* __restrict__ biasAll, unsigned long long* __restrict__ bmask) {
    if (blockIdx.x < 2048) {
        int idx = blockIdx.x * 256 + threadIdx.x;
        for (; idx < M_ * 512 / 8; idx += 2048 * 256) {
            const float4* s = reinterpret_cast<const float4*>(x + (size_t)idx * 8);
            float4 v0 = s[0], v1 = s[1];
            f16x8 o;
            o[0] = (f16)v0.x; o[1] = (f16)v0.y; o[2] = (f16)v0.z; o[3] = (f16)v0.w;
            o[4] = (f16)v1.x; o[5] = (f16)v1.y; o[6] = (f16)v1.z; o[7] = (f16)v1.w;
            *reinterpret_cast<f16x8*>(xh + (size_t)idx * 8) = o;
        }
        return;
    }
    const int tid = (blockIdx.x - 2048) * 256 + threadIdx.x;
    {
        const float* s; f16* d; float sc = 1.0f;
        int pp = tid >> 15, off = tid & 32767;
        if (pp == 0)      { s = Wq; d = Wh;              sc = QSCALE; }
        else if (pp == 1) { s = Wk; d = Wh + 512 * 512; }
        else if (pp == 2) { s = Wv; d = Wh + 2 * 512 * 512; }
        else              { s = Wo; d = Woh; }
        const float4* sv4 = reinterpret_cast<const float4*>(s + (size_t)off * 8);
        float4 v0 = sv4[0], v1 = sv4[1];
        f16x8 o;
        o[0] = (f16)(v0.x * sc); o[1] = (f16)(v0.y * sc);
        o[2] = (f16)(v0.z * sc); o[3] = (f16)(v0.w * sc);
        o[4] = (f16)(v1.x * sc); o[5] = (f16)(v1.y * sc);
        o[6] = (f16)(v1.z * sc); o[7] = (f16)(v1.w * sc);
        *reinterpret_cast<f16x8*>(d + (size_t)off * 8) = o;
    }
    if (tid < 1536) {
        float v = (tid < 512) ? QSCALE * bq[tid] : (tid < 1024) ? bk[tid - 512] : bv[tid - 1024];
        biasAll[tid] = v;
    }
    if (tid < 65536) {
        unsigned long long bal = __ballot(adj[tid] > 0);
        if ((tid & 63) == 0) bmask[tid >> 6] = bal;
    }
}

// ---------------- fused QKV GEMM ----------------

__global__ __launch_bounds__(512) void qkv_gemm(const f16* __restrict__ A, const f16* __restrict__ W,
                                                const float* __restrict__ biasAll,
                                                f16* __restrict__ out, f16* __restrict__ vT) {
    __shared__ __align__(16) f16 lds[65536];
    const int tt = threadIdx.x, wave = tt >> 6, lane = tt & 63;
    const int lb = blockIdx.x, xcd = lb & 7, idx = lb >> 3;
    const int m0 = (xcd * 16 + idx / 6) * 256;
    const int n0 = (idx % 6) * 256;
    f32x4 acc[8][4] = {};
    gemm256_core(A, W, m0, n0, lds, acc, wave, lane);

    const int wr = wave & 1, wc = wave >> 1;
    const int l15 = lane & 15, l4 = lane >> 4;
    f16* epi = lds;
    const bool isV = (n0 >= 1024);
    float bb[4];
#pragma unroll
    for (int bc = 0; bc < 4; ++bc) bb[bc] = biasAll[n0 + wc * 64 + bc * 16 + l15];
#pragma unroll
    for (int half = 0; half < 2; ++half) {
        if (wr == half) {
#pragma unroll
            for (int ar = 0; ar < 8; ++ar)
#pragma unroll
                for (int bc = 0; bc < 4; ++bc)
#pragma unroll
                    for (int r = 0; r < 4; ++r)
                        epi[(ar * 16 + l4 * 4 + r) * 264 + wc * 64 + bc * 16 + l15] =
                            (f16)(acc[ar][bc][r] + bb[bc]);
        }
        LDS_FENCE();
        SBAR();
        if (!isV) {
            const int rr = tt >> 5, slot = tt & 31;
#pragma unroll
            for (int p = 0; p < 8; ++p) {
                int row = p * 16 + rr;
                *reinterpret_cast<f16x8*>(out + (size_t)(m0 + half * 128 + row) * 1024 + n0 + slot * 8) =
                    *reinterpret_cast<const f16x8*>(epi + row * 264 + slot * 8);
            }
        } else {
            // col-pack: vT[(bt*8+h)*64+dk][nf], flat base (n0-1024)*256 within bt panel
            f16* vdst = vT + (size_t)(m0 >> 8) * 8 * 64 * 256 + (size_t)(n0 - 1024) * 256;
            const int col = tt & 255, rh = tt >> 8;
#pragma unroll
            for (int i = 0; i < 8; ++i) {
                int c8 = rh * 8 + i;
                f16x8 v;
#pragma unroll
                for (int e = 0; e < 8; ++e) v[e] = epi[(c8 * 8 + e) * 264 + col];
                int nf0 = half * 128 + c8 * 8;
                *reinterpret_cast<f16x8*>(vdst + (size_t)col * 256 + nf0) = v;
            }
        }
        SBAR();
    }
}

// ---------------- attention (swapped QK^T, in-register P) ----------------
// __launch_bounds__(512, 2): 2 waves/EU -> 256-VGPR cap. The live set (sc[16]=64
// VGPR + frags) needs ~190; R8's (512,4) capped at 128 and R9's unhinted compile
// also chose 128 -> ~25 VGPR/thread spilled to scratch (~270 MB RW). LDS (72 KB)
// limits to 1-2 blocks/CU anyway, so the occupancy pin costs nothing.

template <int NR>
__device__ __forceinline__ void stage_rows512(const f16* __restrict__ g, int ld, int coff,
                                              f16* ldsb, int wave, int lane) {
    const int rr = wave * 8 + (lane >> 3);
    const int p  = lane & 7;
#pragma unroll
    for (int i = 0; i < NR / 64; ++i) {
        int r = i * 64 + rr;
        int col = ((p ^ (r & 7)) << 3);
        GLOAD16(g + (size_t)r * ld + coff + col, ldsb + (i * 64 + wave * 8) * 64);
    }
}

// V^T panel [64 dk][256 nf] viewed as 256 rows (rv = dk*4+chunk) of 64 f16,
// swizzle key = (rv ^ (rv>>3)) & 7 on the 16B slot.
__device__ __forceinline__ void stage_v512(const f16* __restrict__ g, f16* ldsb,
                                           int wave, int lane) {
    const int rr = wave * 8 + (lane >> 3);
    const int p  = lane & 7;
#pragma unroll
    for (int i = 0; i < 4; ++i) {
        int r = i * 64 + rr;
        int key = (r ^ (r >> 3)) & 7;
        GLOAD16(g + (size_t)r * 64 + ((p ^ key) << 3), ldsb + (i * 64 + wave * 8) * 64);
    }
}

__global__ __launch_bounds__(512, 2) void attn_kernel(const f16* __restrict__ qkv,
                                                      const f16* __restrict__ vT,
                                                      const unsigned long long* __restrict__ bmg,
                                                      f16* __restrict__ ao) {
    __shared__ f16 Ks[256 * 64];
    __shared__ f16 Vs[256 * 64];
    __shared__ unsigned long long BMs[1024];
    const int t = threadIdx.x, wave = t >> 6, lane = t & 63;
    const int l15 = lane & 15, l4 = lane >> 4;
    const int bh = blockIdx.x, bt = bh >> 3, h = bh & 7;
    const int btq = bt * 256, hq = h * 64;
    const f16* qb = qkv + (size_t)btq * 1024 + hq;
    const f16* kb = qb + 512;

    stage_rows512<256>(kb, 1024, 0, Ks, wave, lane);
    stage_v512(vT + (size_t)bh * 16384, Vs, wave, lane);
    GLOAD16((const char*)bmg + (size_t)t * 16, (char*)(BMs + wave * 128));
    __syncthreads();

    for (int s = 0; s < 2; ++s) {
        const int qrow_base = wave * 32 + s * 16;

        f16x8 aq[2];
#pragma unroll
        for (int kk = 0; kk < 2; ++kk)
            aq[kk] = *reinterpret_cast<const f16x8*>(
                qb + (size_t)(qrow_base + l15) * 1024 + kk * 32 + l4 * 8);

        // S^T = K·Q^T : lane holds S[k = ct*16 + l4*4 + r][q = qrow_base + l15]
        f32x4 sc[16];
#pragma unroll
        for (int ct = 0; ct < 16; ++ct) sc[ct] = (f32x4){0.f, 0.f, 0.f, 0.f};
#pragma unroll
        for (int ct = 0; ct < 16; ++ct)
#pragma unroll
            for (int kk = 0; kk < 2; ++kk) {
                int rk = ct * 16 + l15;
                int sk = kk * 4 + l4;
                f16x8 bk_ = *reinterpret_cast<const f16x8*>(Ks + rk * 64 + ((sk ^ (rk & 7)) << 3));
                sc[ct] = __builtin_amdgcn_mfma_f32_16x16x32_f16(bk_, aq[kk], sc[ct], 0, 0, 0);
            }

        // softmax in-lane over 64 k-values (q = l15-row), + 2 shuffles across l4-groups
        const int ig = qrow_base + l15;
        const u16x8* mr = reinterpret_cast<const u16x8*>(BMs + ig * 4);
        u16x8 w0 = mr[0], w1 = mr[1];
        float mx = -1e38f;
#pragma unroll
        for (int ct = 0; ct < 16; ++ct)
#pragma unroll
            for (int r = 0; r < 4; ++r) mx = fmaxf(mx, sc[ct][r]);
        mx = fmaxf(mx, __shfl_xor(mx, 16, 64));
        mx = fmaxf(mx, __shfl_xor(mx, 32, 64));
        float sum = 0.f;
#pragma unroll
        for (int ct = 0; ct < 16; ++ct) {
            unsigned mb = ((ct < 8) ? (unsigned)w0[ct] : (unsigned)w1[ct & 7]) >> (l4 * 4);
#pragma unroll
            for (int r = 0; r < 4; ++r) {
                float p = __builtin_exp2f(sc[ct][r] - mx);
                p = ((mb >> r) & 1u) ? p : 0.0f;
                sc[ct][r] = p;
                sum += p;
            }
        }
        sum += __shfl_xor(sum, 16, 64);
        sum += __shfl_xor(sum, 32, 64);
        float rs = 1.0f / sum;
        float rsrow[4];
#pragma unroll
        for (int r = 0; r < 4; ++r) rsrow[r] = __shfl(rs, l4 * 4 + r, 64);

        // PV: k-permutation per MFMA kkp: lane slice = {kkp*32+l4*4+r, kkp*32+16+l4*4+r}
        f32x4 oacc[4] = {};
#pragma unroll
        for (int kkp = 0; kkp < 8; ++kkp) {
            u32x4 up;
            up[0] = __builtin_bit_cast(unsigned int,
                        __builtin_amdgcn_cvt_pkrtz(sc[2 * kkp][0], sc[2 * kkp][1]));
            up[1] = __builtin_bit_cast(unsigned int,
                        __builtin_amdgcn_cvt_pkrtz(sc[2 * kkp][2], sc[2 * kkp][3]));
            up[2] = __builtin_bit_cast(unsigned int,
                        __builtin_amdgcn_cvt_pkrtz(sc[2 * kkp + 1][0], sc[2 * kkp + 1][1]));
            up[3] = __builtin_bit_cast(unsigned int,
                        __builtin_amdgcn_cvt_pkrtz(sc[2 * kkp + 1][2], sc[2 * kkp + 1][3]));
            f16x8 pa = __builtin_bit_cast(f16x8, up);
#pragma unroll
            for (int c2 = 0; c2 < 4; ++c2) {
                int d = c2 * 16 + l15;
                int nf0a = kkp * 32 + l4 * 4;
                int nf0b = nf0a + 16;
                int rvA = d * 4 + (nf0a >> 6), rvB = d * 4 + (nf0b >> 6);
                int keyA = (rvA ^ (rvA >> 3)) & 7, keyB = (rvB ^ (rvB >> 3)) & 7;
                u32x2 va = *reinterpret_cast<const u32x2*>(
                    Vs + rvA * 64 + ((((nf0a >> 3) & 7) ^ keyA) << 3) + (nf0a & 7));
                u32x2 vb = *reinterpret_cast<const u32x2*>(
                    Vs + rvB * 64 + ((((nf0b >> 3) & 7) ^ keyB) << 3) + (nf0b & 7));
                u32x4 uv; uv[0] = va[0]; uv[1] = va[1]; uv[2] = vb[0]; uv[3] = vb[1];
                f16x8 bv_ = __builtin_bit_cast(f16x8, uv);
                oacc[c2] = __builtin_amdgcn_mfma_f32_16x16x32_f16(pa, bv_, oacc[c2], 0, 0, 0);
            }
        }
#pragma unroll
        for (int c2 = 0; c2 < 4; ++c2)
#pragma unroll
            for (int r = 0; r < 4; ++r) {
                int nf = qrow_base + l4 * 4 + r;
                int dcol = hq + c2 * 16 + l15;
                ao[((size_t)btq + nf) * 512 + dcol] = (f16)(oacc[c2][r] * rsrow[r]);
            }
    }
}

// ---------------- output projection (unchanged) ----------------

__global__ __launch_bounds__(512) void o_gemm(const f16* __restrict__ A, const f16* __restrict__ W,
                                              const float* __restrict__ bo, float* __restrict__ out) {
    __shared__ __align__(16) f16 lds[65536];
    const int tt = threadIdx.x, wave = tt >> 6, lane = tt & 63;
    const int lb = blockIdx.x, xcd = lb & 7, idx = lb >> 3;
    const int m0 = (xcd * 16 + idx / 2) * 256;
    const int n0 = (idx % 2) * 256;
    f32x4 acc[8][4] = {};
    gemm256_core(A, W, m0, n0, lds, acc, wave, lane);

    const int wr = wave & 1, wc = wave >> 1;
    const int l15 = lane & 15, l4 = lane >> 4;
    float bb[4];
#pragma unroll
    for (int bc = 0; bc < 4; ++bc) bb[bc] = bo[n0 + wc * 64 + bc * 16 + l15];
#pragma unroll
    for (int ar = 0; ar < 8; ++ar)
#pragma unroll
        for (int bc = 0; bc < 4; ++bc) {
            int ng = n0 + wc * 64 + bc * 16 + l15;
#pragma unroll
            for (int r = 0; r < 4; ++r) {
                int mg = m0 + wr * 128 + ar * 16 + l4 * 4 + r;
                out[(size_t)mg * 512 + ng] = acc[ar][bc][r] + bb[bc];
            }
        }
}

// ---------------- launch ----------------

extern "C" void kernel_launch(void* const* d_in, const int* in_sizes, int n_in,
                              void* d_out, int out_size, void* d_ws, size_t ws_size,
                              hipStream_t stream) {
    const float* x   = (const float*)d_in[0];
    const int*   adj = (const int*)d_in[1];
    const float* Wq  = (const float*)d_in[2];
    const float* bq  = (const float*)d_in[3];
    const float* Wk  = (const float*)d_in[4];
    const float* bk  = (const float*)d_in[5];
    const float* Wv  = (const float*)d_in[6];
    const float* bv  = (const float*)d_in[7];
    const float* Wo  = (const float*)d_in[8];
    const float* bo  = (const float*)d_in[9];
    float* out = (float*)d_out;

    char* ws = (char*)d_ws;
    f16*   Wh      = (f16*)ws;                                        // 1572864 B
    f16*   Woh     = (f16*)(ws + 1572864);                            //  524288 B
    float* biasAll = (float*)(ws + 2097152);                          //    6144 B
    unsigned long long* bmask = (unsigned long long*)(ws + 2103296);  //    8192 B
    f16*   xh      = (f16*)(ws + 2111488);                            // [M][512] f16 (reused as ao)
    f16*   qkvb    = (f16*)(ws + 2111488 + (size_t)M_ * 512 * 2);     // [M][1024] f16 (q|k)
    f16*   vTb     = (f16*)(ws + 2111488 + (size_t)M_ * 512 * 2 + (size_t)M_ * 1024 * 2); // [128][8][64][256]
    f16*   aob     = xh;

    prep_all<<<2560, 256, 0, stream>>>(x, xh, Wq, Wk, Wv, Wo, bq, bk, bv, adj,
                                       Wh, Woh, biasAll, bmask);
    qkv_gemm<<<768, 512, 0, stream>>>(xh, Wh, biasAll, qkvb, vTb);
    attn_kernel<<<128 * H_, 512, 0, stream>>>(qkvb, vTb, bmask, aob);
    o_gemm<<<256, 512, 0, stream>>>(aob, Woh, bo, out);
}

// Round 11
// 242.664 us; speedup vs baseline: 1.0375x; 1.0375x over previous
//
#include <hip/hip_runtime.h>

#define NF 256
#define H_ 8
#define M_ 32768

typedef _Float16 f16;
typedef __fp16 fp16v2 __attribute__((ext_vector_type(2)));
typedef _Float16 f16x8 __attribute__((ext_vector_type(8)));
typedef float f32x4 __attribute__((ext_vector_type(4)));
typedef unsigned short u16x8 __attribute__((ext_vector_type(8)));
typedef unsigned int u32x2 __attribute__((ext_vector_type(2)));
typedef unsigned int u32x4 __attribute__((ext_vector_type(4)));

#define GLOAD16(src, dst) \
  __builtin_amdgcn_global_load_lds((const __attribute__((address_space(1))) void*)(src), \
                                   (__attribute__((address_space(3))) void*)(dst), 16, 0, 0)

#define LDS_FENCE() do { asm volatile("s_waitcnt lgkmcnt(0)" ::: "memory"); \
                         __builtin_amdgcn_sched_barrier(0); } while (0)
#define SBAR() asm volatile("s_barrier" ::: "memory")

// ---------------- 256^2 8-phase GEMM core (unchanged from R5) ----------------

__device__ __forceinline__ void stageHT(const f16* __restrict__ g, int r0, int k0,
                                        f16* ldst, int wave, int lane) {
    const int key = lane >> 3;
    const int colsw = k0 + (((lane & 7) ^ key) << 3);
#pragma unroll
    for (int i = 0; i < 2; ++i) {
        int r = i * 64 + wave * 8 + key;
        GLOAD16(g + (size_t)(r0 + r) * 512 + colsw, ldst + (i * 64 + wave * 8) * 64);
    }
}

__device__ __forceinline__ void gemm256_core(const f16* __restrict__ A, const f16* __restrict__ W,
                                             int m0, int n0, f16* lds,
                                             f32x4 (&acc)[8][4], int wave, int lane) {
    const int wr = wave & 1, wc = wave >> 1;
    const int l15 = lane & 15, l4 = lane >> 4;
    stageHT(W, n0,        0, lds + 16384, wave, lane);
    stageHT(W, n0 + 128,  0, lds + 24576, wave, lane);
    stageHT(A, m0,        0, lds,         wave, lane);
    stageHT(A, m0 + 128,  0, lds + 8192,  wave, lane);
    stageHT(W, n0,       64, lds + 32768 + 16384, wave, lane);
    stageHT(W, n0 + 128, 64, lds + 32768 + 24576, wave, lane);
    asm volatile("s_waitcnt vmcnt(4)" ::: "memory");
    SBAR();
#pragma unroll
    for (int t = 0; t < 8; ++t) {
        f16* bufA = lds + (t & 1) * 32768;
        f16* bufB = bufA + 16384;
        f16* nA   = lds + ((t & 1) ^ 1) * 32768;
        f16x8 bfr[4][2];
#pragma unroll
        for (int j = 0; j < 4; ++j)
#pragma unroll
            for (int kk = 0; kk < 2; ++kk) {
                int rb = wc * 64 + j * 16 + l15;
                bfr[j][kk] = *reinterpret_cast<const f16x8*>(
                    bufB + rb * 64 + ((((kk << 2) + l4) ^ (rb & 7)) << 3));
            }
#pragma unroll
        for (int q = 0; q < 4; ++q) {
            f16x8 afr[2][2];
#pragma unroll
            for (int rf = 0; rf < 2; ++rf)
#pragma unroll
                for (int kk = 0; kk < 2; ++kk) {
                    int ra = wr * 128 + q * 32 + rf * 16 + l15;
                    afr[rf][kk] = *reinterpret_cast<const f16x8*>(
                        bufA + ra * 64 + ((((kk << 2) + l4) ^ (ra & 7)) << 3));
                }
            if (q == 0 && t < 7) stageHT(A, m0,       (t + 1) * 64, nA,          wave, lane);
            if (q == 1 && t < 7) stageHT(A, m0 + 128, (t + 1) * 64, nA + 8192,   wave, lane);
            if (q == 2 && t < 6) stageHT(W, n0,       (t + 2) * 64, bufB,        wave, lane);
            if (q == 3 && t < 6) stageHT(W, n0 + 128, (t + 2) * 64, bufB + 8192, wave, lane);
            SBAR();
            LDS_FENCE();
            __builtin_amdgcn_s_setprio(1);
#pragma unroll
            for (int rf = 0; rf < 2; ++rf)
#pragma unroll
                for (int j = 0; j < 4; ++j)
#pragma unroll
                    for (int kk = 0; kk < 2; ++kk)
                        acc[q * 2 + rf][j] = __builtin_amdgcn_mfma_f32_16x16x32_f16(
                            afr[rf][kk], bfr[j][kk], acc[q * 2 + rf][j], 0, 0, 0);
            __builtin_amdgcn_s_setprio(0);
            if (q < 3) SBAR();
        }
        if (t < 6) { asm volatile("s_waitcnt vmcnt(4)" ::: "memory"); }
        else       { asm volatile("s_waitcnt vmcnt(0)" ::: "memory"); }
        SBAR();
    }
}

// ---------------- conversion / prep ----------------

#define QSCALE 0.1803368801111204f   // (1/8) * log2(e)

__global__ void prep_all(const float* __restrict__ x, f16* __restrict__ xh,
                         const float* __restrict__ Wq, const float* __restrict__ Wk,
                         const float* __restrict__ Wv, const float* __restrict__ Wo,
                         const float* __restrict__ bq, const float* __restrict__ bk,
                         const float* __restrict__ bv, const int* __restrict__ adj,
                         f16* __restrict__ Wh, f16* __restrict__ Woh,
                         float* __restrict__ biasAll, unsigned long long* __restrict__ bmask) {
    if (blockIdx.x < 2048) {
        int idx = blockIdx.x * 256 + threadIdx.x;
        for (; idx < M_ * 512 / 8; idx += 2048 * 256) {
            const float4* s = reinterpret_cast<const float4*>(x + (size_t)idx * 8);
            float4 v0 = s[0], v1 = s[1];
            f16x8 o;
            o[0] = (f16)v0.x; o[1] = (f16)v0.y; o[2] = (f16)v0.z; o[3] = (f16)v0.w;
            o[4] = (f16)v1.x; o[5] = (f16)v1.y; o[6] = (f16)v1.z; o[7] = (f16)v1.w;
            *reinterpret_cast<f16x8*>(xh + (size_t)idx * 8) = o;
        }
        return;
    }
    const int tid = (blockIdx.x - 2048) * 256 + threadIdx.x;
    {
        const float* s; f16* d; float sc = 1.0f;
        int pp = tid >> 15, off = tid & 32767;
        if (pp == 0)      { s = Wq; d = Wh;              sc = QSCALE; }
        else if (pp == 1) { s = Wk; d = Wh + 512 * 512; }
        else if (pp == 2) { s = Wv; d = Wh + 2 * 512 * 512; }
        else              { s = Wo; d = Woh; }
        const float4* sv4 = reinterpret_cast<const float4*>(s + (size_t)off * 8);
        float4 v0 = sv4[0], v1 = sv4[1];
        f16x8 o;
        o[0] = (f16)(v0.x * sc); o[1] = (f16)(v0.y * sc);
        o[2] = (f16)(v0.z * sc); o[3] = (f16)(v0.w * sc);
        o[4] = (f16)(v1.x * sc); o[5] = (f16)(v1.y * sc);
        o[6] = (f16)(v1.z * sc); o[7] = (f16)(v1.w * sc);
        *reinterpret_cast<f16x8*>(d + (size_t)off * 8) = o;
    }
    if (tid < 1536) {
        float v = (tid < 512) ? QSCALE * bq[tid] : (tid < 1024) ? bk[tid - 512] : bv[tid - 1024];
        biasAll[tid] = v;
    }
    if (tid < 65536) {
        unsigned long long bal = __ballot(adj[tid] > 0);
        if ((tid & 63) == 0) bmask[tid >> 6] = bal;
    }
}

// ---------------- fused QKV GEMM ----------------

__global__ __launch_bounds__(512) void qkv_gemm(const f16* __restrict__ A, const f16* __restrict__ W,
                                                const float* __restrict__ biasAll,
                                                f16* __restrict__ out, f16* __restrict__ vT) {
    __shared__ __align__(16) f16 lds[65536];
    const int tt = threadIdx.x, wave = tt >> 6, lane = tt & 63;
    const int lb = blockIdx.x, xcd = lb & 7, idx = lb >> 3;
    const int m0 = (xcd * 16 + idx / 6) * 256;
    const int n0 = (idx % 6) * 256;
    f32x4 acc[8][4] = {};
    gemm256_core(A, W, m0, n0, lds, acc, wave, lane);

    const int wr = wave & 1, wc = wave >> 1;
    const int l15 = lane & 15, l4 = lane >> 4;
    f16* epi = lds;
    const bool isV = (n0 >= 1024);
    float bb[4];
#pragma unroll
    for (int bc = 0; bc < 4; ++bc) bb[bc] = biasAll[n0 + wc * 64 + bc * 16 + l15];
#pragma unroll
    for (int half = 0; half < 2; ++half) {
        if (wr == half) {
#pragma unroll
            for (int ar = 0; ar < 8; ++ar)
#pragma unroll
                for (int bc = 0; bc < 4; ++bc)
#pragma unroll
                    for (int r = 0; r < 4; ++r)
                        epi[(ar * 16 + l4 * 4 + r) * 264 + wc * 64 + bc * 16 + l15] =
                            (f16)(acc[ar][bc][r] + bb[bc]);
        }
        LDS_FENCE();
        SBAR();
        if (!isV) {
            const int rr = tt >> 5, slot = tt & 31;
#pragma unroll
            for (int p = 0; p < 8; ++p) {
                int row = p * 16 + rr;
                *reinterpret_cast<f16x8*>(out + (size_t)(m0 + half * 128 + row) * 1024 + n0 + slot * 8) =
                    *reinterpret_cast<const f16x8*>(epi + row * 264 + slot * 8);
            }
        } else {
            // col-pack: vT[(bt*8+h)*64+dk][nf], flat base (n0-1024)*256 within bt panel
            f16* vdst = vT + (size_t)(m0 >> 8) * 8 * 64 * 256 + (size_t)(n0 - 1024) * 256;
            const int col = tt & 255, rh = tt >> 8;
#pragma unroll
            for (int i = 0; i < 8; ++i) {
                int c8 = rh * 8 + i;
                f16x8 v;
#pragma unroll
                for (int e = 0; e < 8; ++e) v[e] = epi[(c8 * 8 + e) * 264 + col];
                int nf0 = half * 128 + c8 * 8;
                *reinterpret_cast<f16x8*>(vdst + (size_t)col * 256 + nf0) = v;
            }
        }
        SBAR();
    }
}

// ---------------- attention (swapped QK^T, in-register P) ----------------
// Live-set discipline: sc[16] (64 VGPR f32) is drained IMMEDIATELY after the
// max-reduce — exp2+mask+sum+cvt_pkrtz pack into pu8[8] (16 VGPR f16). PV then
// holds only pu8+oacc+V-frags. Peak live ~100 VGPR < 128 -> no spill at any cap.
// (R8-R10 lesson: keeping all 64 P-values in f32 through PV spilled ~400 B/thread
// = 250-500 MB of scratch HBM traffic regardless of __launch_bounds__ hints.)

template <int NR>
__device__ __forceinline__ void stage_rows512(const f16* __restrict__ g, int ld, int coff,
                                              f16* ldsb, int wave, int lane) {
    const int rr = wave * 8 + (lane >> 3);
    const int p  = lane & 7;
#pragma unroll
    for (int i = 0; i < NR / 64; ++i) {
        int r = i * 64 + rr;
        int col = ((p ^ (r & 7)) << 3);
        GLOAD16(g + (size_t)r * ld + coff + col, ldsb + (i * 64 + wave * 8) * 64);
    }
}

// V^T panel [64 dk][256 nf] viewed as 256 rows (rv = dk*4+chunk) of 64 f16,
// swizzle key = (rv ^ (rv>>3)) & 7 on the 16B slot.
__device__ __forceinline__ void stage_v512(const f16* __restrict__ g, f16* ldsb,
                                           int wave, int lane) {
    const int rr = wave * 8 + (lane >> 3);
    const int p  = lane & 7;
#pragma unroll
    for (int i = 0; i < 4; ++i) {
        int r = i * 64 + rr;
        int key = (r ^ (r >> 3)) & 7;
        GLOAD16(g + (size_t)r * 64 + ((p ^ key) << 3), ldsb + (i * 64 + wave * 8) * 64);
    }
}

__global__ __launch_bounds__(512, 2) void attn_kernel(const f16* __restrict__ qkv,
                                                      const f16* __restrict__ vT,
                                                      const unsigned long long* __restrict__ bmg,
                                                      f16* __restrict__ ao) {
    __shared__ f16 Ks[256 * 64];
    __shared__ f16 Vs[256 * 64];
    __shared__ unsigned long long BMs[1024];
    const int t = threadIdx.x, wave = t >> 6, lane = t & 63;
    const int l15 = lane & 15, l4 = lane >> 4;
    const int bh = blockIdx.x, bt = bh >> 3, h = bh & 7;
    const int btq = bt * 256, hq = h * 64;
    const f16* qb = qkv + (size_t)btq * 1024 + hq;
    const f16* kb = qb + 512;

    stage_rows512<256>(kb, 1024, 0, Ks, wave, lane);
    stage_v512(vT + (size_t)bh * 16384, Vs, wave, lane);
    GLOAD16((const char*)bmg + (size_t)t * 16, (char*)(BMs + wave * 128));
    __syncthreads();

    for (int s = 0; s < 2; ++s) {
        const int qrow_base = wave * 32 + s * 16;

        f16x8 aq[2];
#pragma unroll
        for (int kk = 0; kk < 2; ++kk)
            aq[kk] = *reinterpret_cast<const f16x8*>(
                qb + (size_t)(qrow_base + l15) * 1024 + kk * 32 + l4 * 8);

        // S^T = K·Q^T : lane holds S[k = ct*16 + l4*4 + r][q = qrow_base + l15]
        f32x4 sc[16];
#pragma unroll
        for (int ct = 0; ct < 16; ++ct) sc[ct] = (f32x4){0.f, 0.f, 0.f, 0.f};
#pragma unroll
        for (int ct = 0; ct < 16; ++ct)
#pragma unroll
            for (int kk = 0; kk < 2; ++kk) {
                int rk = ct * 16 + l15;
                int sk = kk * 4 + l4;
                f16x8 bk_ = *reinterpret_cast<const f16x8*>(Ks + rk * 64 + ((sk ^ (rk & 7)) << 3));
                sc[ct] = __builtin_amdgcn_mfma_f32_16x16x32_f16(bk_, aq[kk], sc[ct], 0, 0, 0);
            }

        // max over raw 64 k-values in-lane + 2 shuffles (shift-invariance: mask later)
        float mx = -1e38f;
#pragma unroll
        for (int ct = 0; ct < 16; ++ct)
#pragma unroll
            for (int r = 0; r < 4; ++r) mx = fmaxf(mx, sc[ct][r]);
        mx = fmaxf(mx, __shfl_xor(mx, 16, 64));
        mx = fmaxf(mx, __shfl_xor(mx, 32, 64));

        // drain sc: exp2 + mask + sum + pack to f16 immediately (sc regs die here)
        const int ig = qrow_base + l15;
        const u16x8* mr = reinterpret_cast<const u16x8*>(BMs + ig * 4);
        u16x8 w0 = mr[0], w1 = mr[1];
        f16x8 pu8[8];
        float sum = 0.f;
#pragma unroll
        for (int c2t = 0; c2t < 8; ++c2t) {
            const int ctA = 2 * c2t, ctB = 2 * c2t + 1;
            unsigned mbA = ((c2t < 4) ? (unsigned)w0[ctA] : (unsigned)w1[ctA & 7]) >> (l4 * 4);
            unsigned mbB = ((c2t < 4) ? (unsigned)w0[ctB] : (unsigned)w1[ctB & 7]) >> (l4 * 4);
            float pA0 = __builtin_exp2f(sc[ctA][0] - mx); pA0 = ((mbA >> 0) & 1u) ? pA0 : 0.0f;
            float pA1 = __builtin_exp2f(sc[ctA][1] - mx); pA1 = ((mbA >> 1) & 1u) ? pA1 : 0.0f;
            float pA2 = __builtin_exp2f(sc[ctA][2] - mx); pA2 = ((mbA >> 2) & 1u) ? pA2 : 0.0f;
            float pA3 = __builtin_exp2f(sc[ctA][3] - mx); pA3 = ((mbA >> 3) & 1u) ? pA3 : 0.0f;
            float pB0 = __builtin_exp2f(sc[ctB][0] - mx); pB0 = ((mbB >> 0) & 1u) ? pB0 : 0.0f;
            float pB1 = __builtin_exp2f(sc[ctB][1] - mx); pB1 = ((mbB >> 1) & 1u) ? pB1 : 0.0f;
            float pB2 = __builtin_exp2f(sc[ctB][2] - mx); pB2 = ((mbB >> 2) & 1u) ? pB2 : 0.0f;
            float pB3 = __builtin_exp2f(sc[ctB][3] - mx); pB3 = ((mbB >> 3) & 1u) ? pB3 : 0.0f;
            sum += (pA0 + pA1) + (pA2 + pA3) + (pB0 + pB1) + (pB2 + pB3);
            u32x4 up;
            up[0] = __builtin_bit_cast(unsigned int, __builtin_amdgcn_cvt_pkrtz(pA0, pA1));
            up[1] = __builtin_bit_cast(unsigned int, __builtin_amdgcn_cvt_pkrtz(pA2, pA3));
            up[2] = __builtin_bit_cast(unsigned int, __builtin_amdgcn_cvt_pkrtz(pB0, pB1));
            up[3] = __builtin_bit_cast(unsigned int, __builtin_amdgcn_cvt_pkrtz(pB2, pB3));
            pu8[c2t] = __builtin_bit_cast(f16x8, up);
        }
        sum += __shfl_xor(sum, 16, 64);
        sum += __shfl_xor(sum, 32, 64);
        float rs = 1.0f / sum;
        float rsrow[4];
#pragma unroll
        for (int r = 0; r < 4; ++r) rsrow[r] = __shfl(rs, l4 * 4 + r, 64);

        // PV: k-permutation per MFMA kkp: lane slice = {kkp*32+l4*4+r, kkp*32+16+l4*4+r}
        f32x4 oacc[4] = {};
#pragma unroll
        for (int kkp = 0; kkp < 8; ++kkp) {
            f16x8 pa = pu8[kkp];
#pragma unroll
            for (int c2 = 0; c2 < 4; ++c2) {
                int d = c2 * 16 + l15;
                int nf0a = kkp * 32 + l4 * 4;
                int nf0b = nf0a + 16;
                int rvA = d * 4 + (nf0a >> 6), rvB = d * 4 + (nf0b >> 6);
                int keyA = (rvA ^ (rvA >> 3)) & 7, keyB = (rvB ^ (rvB >> 3)) & 7;
                u32x2 va = *reinterpret_cast<const u32x2*>(
                    Vs + rvA * 64 + ((((nf0a >> 3) & 7) ^ keyA) << 3) + (nf0a & 7));
                u32x2 vb = *reinterpret_cast<const u32x2*>(
                    Vs + rvB * 64 + ((((nf0b >> 3) & 7) ^ keyB) << 3) + (nf0b & 7));
                u32x4 uv; uv[0] = va[0]; uv[1] = va[1]; uv[2] = vb[0]; uv[3] = vb[1];
                f16x8 bv_ = __builtin_bit_cast(f16x8, uv);
                oacc[c2] = __builtin_amdgcn_mfma_f32_16x16x32_f16(pa, bv_, oacc[c2], 0, 0, 0);
            }
        }
#pragma unroll
        for (int c2 = 0; c2 < 4; ++c2)
#pragma unroll
            for (int r = 0; r < 4; ++r) {
                int nf = qrow_base + l4 * 4 + r;
                int dcol = hq + c2 * 16 + l15;
                ao[((size_t)btq + nf) * 512 + dcol] = (f16)(oacc[c2][r] * rsrow[r]);
            }
    }
}

// ---------------- output projection (unchanged) ----------------

__global__ __launch_bounds__(512) void o_gemm(const f16* __restrict__ A, const f16* __restrict__ W,
                                              const float* __restrict__ bo, float* __restrict__ out) {
    __shared__ __align__(16) f16 lds[65536];
    const int tt = threadIdx.x, wave = tt >> 6, lane = tt & 63;
    const int lb = blockIdx.x, xcd = lb & 7, idx = lb >> 3;
    const int m0 = (xcd * 16 + idx / 2) * 256;
    const int n0 = (idx % 2) * 256;
    f32x4 acc[8][4] = {};
    gemm256_core(A, W, m0, n0, lds, acc, wave, lane);

    const int wr = wave & 1, wc = wave >> 1;
    const int l15 = lane & 15, l4 = lane >> 4;
    float bb[4];
#pragma unroll
    for (int bc = 0; bc < 4; ++bc) bb[bc] = bo[n0 + wc * 64 + bc * 16 + l15];
#pragma unroll
    for (int ar = 0; ar < 8; ++ar)
#pragma unroll
        for (int bc = 0; bc < 4; ++bc) {
            int ng = n0 + wc * 64 + bc * 16 + l15;
#pragma unroll
            for (int r = 0; r < 4; ++r) {
                int mg = m0 + wr * 128 + ar * 16 + l4 * 4 + r;
                out[(size_t)mg * 512 + ng] = acc[ar][bc][r] + bb[bc];
            }
        }
}

// ---------------- launch ----------------

extern "C" void kernel_launch(void* const* d_in, const int* in_sizes, int n_in,
                              void* d_out, int out_size, void* d_ws, size_t ws_size,
                              hipStream_t stream) {
    const float* x   = (const float*)d_in[0];
    const int*   adj = (const int*)d_in[1];
    const float* Wq  = (const float*)d_in[2];
    const float* bq  = (const float*)d_in[3];
    const float* Wk  = (const float*)d_in[4];
    const float* bk  = (const float*)d_in[5];
    const float* Wv  = (const float*)d_in[6];
    const float* bv  = (const float*)d_in[7];
    const float* Wo  = (const float*)d_in[8];
    const float* bo  = (const float*)d_in[9];
    float* out = (float*)d_out;

    char* ws = (char*)d_ws;
    f16*   Wh      = (f16*)ws;                                        // 1572864 B
    f16*   Woh     = (f16*)(ws + 1572864);                            //  524288 B
    float* biasAll = (float*)(ws + 2097152);                          //    6144 B
    unsigned long long* bmask = (unsigned long long*)(ws + 2103296);  //    8192 B
    f16*   xh      = (f16*)(ws + 2111488);                            // [M][512] f16 (reused as ao)
    f16*   qkvb    = (f16*)(ws + 2111488 + (size_t)M_ * 512 * 2);     // [M][1024] f16 (q|k)
    f16*   vTb     = (f16*)(ws + 2111488 + (size_t)M_ * 512 * 2 + (size_t)M_ * 1024 * 2); // [128][8][64][256]
    f16*   aob     = xh;

    prep_all<<<2560, 256, 0, stream>>>(x, xh, Wq, Wk, Wv, Wo, bq, bk, bv, adj,
                                       Wh, Woh, biasAll, bmask);
    qkv_gemm<<<768, 512, 0, stream>>>(xh, Wh, biasAll, qkvb, vTb);
    attn_kernel<<<128 * H_, 512, 0, stream>>>(qkvb, vTb, bmask, aob);
    o_gemm<<<256, 512, 0, stream>>>(aob, Woh, bo, out);
}

// Round 12
// 175.066 us; speedup vs baseline: 1.4381x; 1.3861x over previous
//
#include <hip/hip_runtime.h>

#define NF 256
#define H_ 8
#define M_ 32768

typedef _Float16 f16;
typedef __fp16 fp16v2 __attribute__((ext_vector_type(2)));
typedef _Float16 f16x8 __attribute__((ext_vector_type(8)));
typedef float f32x4 __attribute__((ext_vector_type(4)));
typedef unsigned short u16x8 __attribute__((ext_vector_type(8)));
typedef unsigned int u32x2 __attribute__((ext_vector_type(2)));
typedef unsigned int u32x4 __attribute__((ext_vector_type(4)));

#define GLOAD16(src, dst) \
  __builtin_amdgcn_global_load_lds((const __attribute__((address_space(1))) void*)(src), \
                                   (__attribute__((address_space(3))) void*)(dst), 16, 0, 0)

#define LDS_FENCE() do { asm volatile("s_waitcnt lgkmcnt(0)" ::: "memory"); \
                         __builtin_amdgcn_sched_barrier(0); } while (0)
#define SBAR() asm volatile("s_barrier" ::: "memory")

// ---------------- 256^2 8-phase GEMM core (unchanged from R5) ----------------

__device__ __forceinline__ void stageHT(const f16* __restrict__ g, int r0, int k0,
                                        f16* ldst, int wave, int lane) {
    const int key = lane >> 3;
    const int colsw = k0 + (((lane & 7) ^ key) << 3);
#pragma unroll
    for (int i = 0; i < 2; ++i) {
        int r = i * 64 + wave * 8 + key;
        GLOAD16(g + (size_t)(r0 + r) * 512 + colsw, ldst + (i * 64 + wave * 8) * 64);
    }
}

__device__ __forceinline__ void gemm256_core(const f16* __restrict__ A, const f16* __restrict__ W,
                                             int m0, int n0, f16* lds,
                                             f32x4 (&acc)[8][4], int wave, int lane) {
    const int wr = wave & 1, wc = wave >> 1;
    const int l15 = lane & 15, l4 = lane >> 4;
    stageHT(W, n0,        0, lds + 16384, wave, lane);
    stageHT(W, n0 + 128,  0, lds + 24576, wave, lane);
    stageHT(A, m0,        0, lds,         wave, lane);
    stageHT(A, m0 + 128,  0, lds + 8192,  wave, lane);
    stageHT(W, n0,       64, lds + 32768 + 16384, wave, lane);
    stageHT(W, n0 + 128, 64, lds + 32768 + 24576, wave, lane);
    asm volatile("s_waitcnt vmcnt(4)" ::: "memory");
    SBAR();
#pragma unroll
    for (int t = 0; t < 8; ++t) {
        f16* bufA = lds + (t & 1) * 32768;
        f16* bufB = bufA + 16384;
        f16* nA   = lds + ((t & 1) ^ 1) * 32768;
        f16x8 bfr[4][2];
#pragma unroll
        for (int j = 0; j < 4; ++j)
#pragma unroll
            for (int kk = 0; kk < 2; ++kk) {
                int rb = wc * 64 + j * 16 + l15;
                bfr[j][kk] = *reinterpret_cast<const f16x8*>(
                    bufB + rb * 64 + ((((kk << 2) + l4) ^ (rb & 7)) << 3));
            }
#pragma unroll
        for (int q = 0; q < 4; ++q) {
            f16x8 afr[2][2];
#pragma unroll
            for (int rf = 0; rf < 2; ++rf)
#pragma unroll
                for (int kk = 0; kk < 2; ++kk) {
                    int ra = wr * 128 + q * 32 + rf * 16 + l15;
                    afr[rf][kk] = *reinterpret_cast<const f16x8*>(
                        bufA + ra * 64 + ((((kk << 2) + l4) ^ (ra & 7)) << 3));
                }
            if (q == 0 && t < 7) stageHT(A, m0,       (t + 1) * 64, nA,          wave, lane);
            if (q == 1 && t < 7) stageHT(A, m0 + 128, (t + 1) * 64, nA + 8192,   wave, lane);
            if (q == 2 && t < 6) stageHT(W, n0,       (t + 2) * 64, bufB,        wave, lane);
            if (q == 3 && t < 6) stageHT(W, n0 + 128, (t + 2) * 64, bufB + 8192, wave, lane);
            SBAR();
            LDS_FENCE();
            __builtin_amdgcn_s_setprio(1);
#pragma unroll
            for (int rf = 0; rf < 2; ++rf)
#pragma unroll
                for (int j = 0; j < 4; ++j)
#pragma unroll
                    for (int kk = 0; kk < 2; ++kk)
                        acc[q * 2 + rf][j] = __builtin_amdgcn_mfma_f32_16x16x32_f16(
                            afr[rf][kk], bfr[j][kk], acc[q * 2 + rf][j], 0, 0, 0);
            __builtin_amdgcn_s_setprio(0);
            if (q < 3) SBAR();
        }
        if (t < 6) { asm volatile("s_waitcnt vmcnt(4)" ::: "memory"); }
        else       { asm volatile("s_waitcnt vmcnt(0)" ::: "memory"); }
        SBAR();
    }
}

// ---------------- conversion / prep ----------------

#define QSCALE 0.1803368801111204f   // (1/8) * log2(e)

__global__ void prep_all(const float* __restrict__ x, f16* __restrict__ xh,
                         const float* __restrict__ Wq, const float* __restrict__ Wk,
                         const float* __restrict__ Wv, const float* __restrict__ Wo,
                         const float* __restrict__ bq, const float* __restrict__ bk,
                         const float* __restrict__ bv, const int* __restrict__ adj,
                         f16* __restrict__ Wh, f16* __restrict__ Woh,
                         float* __restrict__ biasAll, unsigned long long* __restrict__ bmask) {
    if (blockIdx.x < 2048) {
        int idx = blockIdx.x * 256 + threadIdx.x;
        for (; idx < M_ * 512 / 8; idx += 2048 * 256) {
            const float4* s = reinterpret_cast<const float4*>(x + (size_t)idx * 8);
            float4 v0 = s[0], v1 = s[1];
            f16x8 o;
            o[0] = (f16)v0.x; o[1] = (f16)v0.y; o[2] = (f16)v0.z; o[3] = (f16)v0.w;
            o[4] = (f16)v1.x; o[5] = (f16)v1.y; o[6] = (f16)v1.z; o[7] = (f16)v1.w;
            *reinterpret_cast<f16x8*>(xh + (size_t)idx * 8) = o;
        }
        return;
    }
    const int tid = (blockIdx.x - 2048) * 256 + threadIdx.x;
    {
        const float* s; f16* d; float sc = 1.0f;
        int pp = tid >> 15, off = tid & 32767;
        if (pp == 0)      { s = Wq; d = Wh;              sc = QSCALE; }
        else if (pp == 1) { s = Wk; d = Wh + 512 * 512; }
        else if (pp == 2) { s = Wv; d = Wh + 2 * 512 * 512; }
        else              { s = Wo; d = Woh; }
        const float4* sv4 = reinterpret_cast<const float4*>(s + (size_t)off * 8);
        float4 v0 = sv4[0], v1 = sv4[1];
        f16x8 o;
        o[0] = (f16)(v0.x * sc); o[1] = (f16)(v0.y * sc);
        o[2] = (f16)(v0.z * sc); o[3] = (f16)(v0.w * sc);
        o[4] = (f16)(v1.x * sc); o[5] = (f16)(v1.y * sc);
        o[6] = (f16)(v1.z * sc); o[7] = (f16)(v1.w * sc);
        *reinterpret_cast<f16x8*>(d + (size_t)off * 8) = o;
    }
    if (tid < 1536) {
        float v = (tid < 512) ? QSCALE * bq[tid] : (tid < 1024) ? bk[tid - 512] : bv[tid - 1024];
        biasAll[tid] = v;
    }
    if (tid < 65536) {
        unsigned long long bal = __ballot(adj[tid] > 0);
        if ((tid & 63) == 0) bmask[tid >> 6] = bal;
    }
}

// ---------------- fused QKV GEMM ----------------

__global__ __launch_bounds__(512) void qkv_gemm(const f16* __restrict__ A, const f16* __restrict__ W,
                                                const float* __restrict__ biasAll,
                                                f16* __restrict__ out, f16* __restrict__ vT) {
    __shared__ __align__(16) f16 lds[65536];
    const int tt = threadIdx.x, wave = tt >> 6, lane = tt & 63;
    const int lb = blockIdx.x, xcd = lb & 7, idx = lb >> 3;
    const int m0 = (xcd * 16 + idx / 6) * 256;
    const int n0 = (idx % 6) * 256;
    f32x4 acc[8][4] = {};
    gemm256_core(A, W, m0, n0, lds, acc, wave, lane);

    const int wr = wave & 1, wc = wave >> 1;
    const int l15 = lane & 15, l4 = lane >> 4;
    f16* epi = lds;
    const bool isV = (n0 >= 1024);
    float bb[4];
#pragma unroll
    for (int bc = 0; bc < 4; ++bc) bb[bc] = biasAll[n0 + wc * 64 + bc * 16 + l15];
#pragma unroll
    for (int half = 0; half < 2; ++half) {
        if (wr == half) {
#pragma unroll
            for (int ar = 0; ar < 8; ++ar)
#pragma unroll
                for (int bc = 0; bc < 4; ++bc)
#pragma unroll
                    for (int r = 0; r < 4; ++r)
                        epi[(ar * 16 + l4 * 4 + r) * 264 + wc * 64 + bc * 16 + l15] =
                            (f16)(acc[ar][bc][r] + bb[bc]);
        }
        LDS_FENCE();
        SBAR();
        if (!isV) {
            const int rr = tt >> 5, slot = tt & 31;
#pragma unroll
            for (int p = 0; p < 8; ++p) {
                int row = p * 16 + rr;
                *reinterpret_cast<f16x8*>(out + (size_t)(m0 + half * 128 + row) * 1024 + n0 + slot * 8) =
                    *reinterpret_cast<const f16x8*>(epi + row * 264 + slot * 8);
            }
        } else {
            // col-pack: vT[(bt*8+h)*64+dk][nf], flat base (n0-1024)*256 within bt panel
            f16* vdst = vT + (size_t)(m0 >> 8) * 8 * 64 * 256 + (size_t)(n0 - 1024) * 256;
            const int col = tt & 255, rh = tt >> 8;
#pragma unroll
            for (int i = 0; i < 8; ++i) {
                int c8 = rh * 8 + i;
                f16x8 v;
#pragma unroll
                for (int e = 0; e < 8; ++e) v[e] = epi[(c8 * 8 + e) * 264 + col];
                int nf0 = half * 128 + c8 * 8;
                *reinterpret_cast<f16x8*>(vdst + (size_t)col * 256 + nf0) = v;
            }
        }
        SBAR();
    }
}

// ---------------- attention (swapped QK^T, fused per-kkp drain+PV) ----------------
// Live-set discipline (R9-R11 lesson: gfx950 splits the reg budget into arch-VGPR
// + AGPR halves for MFMA kernels; usable arch space ~128, and scheduler hoisting
// of all 64 PV ds_reads + all P-packs blew the peak to ~200 -> 250-400 B/thread
// scratch spill). Fix: each kkp iteration consumes its sc pair (exp2+mask+sum+
// pack) and immediately runs its 4 MFMAs; sched_barrier(0) at iteration end
// forbids cross-iteration hoisting. No pu8 array exists; peak live ~95 arch regs.

template <int NR>
__device__ __forceinline__ void stage_rows512(const f16* __restrict__ g, int ld, int coff,
                                              f16* ldsb, int wave, int lane) {
    const int rr = wave * 8 + (lane >> 3);
    const int p  = lane & 7;
#pragma unroll
    for (int i = 0; i < NR / 64; ++i) {
        int r = i * 64 + rr;
        int col = ((p ^ (r & 7)) << 3);
        GLOAD16(g + (size_t)r * ld + coff + col, ldsb + (i * 64 + wave * 8) * 64);
    }
}

// V^T panel [64 dk][256 nf] viewed as 256 rows (rv = dk*4+chunk) of 64 f16,
// swizzle key = (rv ^ (rv>>3)) & 7 on the 16B slot.
__device__ __forceinline__ void stage_v512(const f16* __restrict__ g, f16* ldsb,
                                           int wave, int lane) {
    const int rr = wave * 8 + (lane >> 3);
    const int p  = lane & 7;
#pragma unroll
    for (int i = 0; i < 4; ++i) {
        int r = i * 64 + rr;
        int key = (r ^ (r >> 3)) & 7;
        GLOAD16(g + (size_t)r * 64 + ((p ^ key) << 3), ldsb + (i * 64 + wave * 8) * 64);
    }
}

__global__ __launch_bounds__(512, 2) void attn_kernel(const f16* __restrict__ qkv,
                                                      const f16* __restrict__ vT,
                                                      const unsigned long long* __restrict__ bmg,
                                                      f16* __restrict__ ao) {
    __shared__ f16 Ks[256 * 64];
    __shared__ f16 Vs[256 * 64];
    __shared__ unsigned long long BMs[1024];
    const int t = threadIdx.x, wave = t >> 6, lane = t & 63;
    const int l15 = lane & 15, l4 = lane >> 4;
    const int bh = blockIdx.x, bt = bh >> 3, h = bh & 7;
    const int btq = bt * 256, hq = h * 64;
    const f16* qb = qkv + (size_t)btq * 1024 + hq;
    const f16* kb = qb + 512;

    stage_rows512<256>(kb, 1024, 0, Ks, wave, lane);
    stage_v512(vT + (size_t)bh * 16384, Vs, wave, lane);
    GLOAD16((const char*)bmg + (size_t)t * 16, (char*)(BMs + wave * 128));
    __syncthreads();

    for (int s = 0; s < 2; ++s) {
        const int qrow_base = wave * 32 + s * 16;

        f16x8 aq[2];
#pragma unroll
        for (int kk = 0; kk < 2; ++kk)
            aq[kk] = *reinterpret_cast<const f16x8*>(
                qb + (size_t)(qrow_base + l15) * 1024 + kk * 32 + l4 * 8);

        // S^T = K·Q^T : lane holds S[k = ct*16 + l4*4 + r][q = qrow_base + l15]
        f32x4 sc[16];
#pragma unroll
        for (int ct = 0; ct < 16; ++ct) sc[ct] = (f32x4){0.f, 0.f, 0.f, 0.f};
#pragma unroll
        for (int ct = 0; ct < 16; ++ct)
#pragma unroll
            for (int kk = 0; kk < 2; ++kk) {
                int rk = ct * 16 + l15;
                int sk = kk * 4 + l4;
                f16x8 bk_ = *reinterpret_cast<const f16x8*>(Ks + rk * 64 + ((sk ^ (rk & 7)) << 3));
                sc[ct] = __builtin_amdgcn_mfma_f32_16x16x32_f16(bk_, aq[kk], sc[ct], 0, 0, 0);
            }

        // max over raw 64 k-values in-lane + 2 shuffles (shift-invariance: mask later)
        float mx = -1e38f;
#pragma unroll
        for (int ct = 0; ct < 16; ++ct)
#pragma unroll
            for (int r = 0; r < 4; ++r) mx = fmaxf(mx, sc[ct][r]);
        mx = fmaxf(mx, __shfl_xor(mx, 16, 64));
        mx = fmaxf(mx, __shfl_xor(mx, 32, 64));

        const int ig = qrow_base + l15;
        const u16x8* mr = reinterpret_cast<const u16x8*>(BMs + ig * 4);
        u16x8 w0 = mr[0], w1 = mr[1];

        // fused drain + PV: per kkp, consume sc pair -> pack pa -> 4 MFMAs.
        // sched_barrier(0) bounds the scheduler's live window to one iteration.
        f32x4 oacc[4] = {};
        float sum = 0.f;
#pragma unroll
        for (int kkp = 0; kkp < 8; ++kkp) {
            const int ctA = 2 * kkp, ctB = 2 * kkp + 1;
            unsigned mbA = ((kkp < 4) ? (unsigned)w0[ctA] : (unsigned)w1[ctA & 7]) >> (l4 * 4);
            unsigned mbB = ((kkp < 4) ? (unsigned)w0[ctB] : (unsigned)w1[ctB & 7]) >> (l4 * 4);
            float pA0 = __builtin_exp2f(sc[ctA][0] - mx); pA0 = ((mbA >> 0) & 1u) ? pA0 : 0.0f;
            float pA1 = __builtin_exp2f(sc[ctA][1] - mx); pA1 = ((mbA >> 1) & 1u) ? pA1 : 0.0f;
            float pA2 = __builtin_exp2f(sc[ctA][2] - mx); pA2 = ((mbA >> 2) & 1u) ? pA2 : 0.0f;
            float pA3 = __builtin_exp2f(sc[ctA][3] - mx); pA3 = ((mbA >> 3) & 1u) ? pA3 : 0.0f;
            float pB0 = __builtin_exp2f(sc[ctB][0] - mx); pB0 = ((mbB >> 0) & 1u) ? pB0 : 0.0f;
            float pB1 = __builtin_exp2f(sc[ctB][1] - mx); pB1 = ((mbB >> 1) & 1u) ? pB1 : 0.0f;
            float pB2 = __builtin_exp2f(sc[ctB][2] - mx); pB2 = ((mbB >> 2) & 1u) ? pB2 : 0.0f;
            float pB3 = __builtin_exp2f(sc[ctB][3] - mx); pB3 = ((mbB >> 3) & 1u) ? pB3 : 0.0f;
            sum += (pA0 + pA1) + (pA2 + pA3) + (pB0 + pB1) + (pB2 + pB3);
            u32x4 up;
            up[0] = __builtin_bit_cast(unsigned int, __builtin_amdgcn_cvt_pkrtz(pA0, pA1));
            up[1] = __builtin_bit_cast(unsigned int, __builtin_amdgcn_cvt_pkrtz(pA2, pA3));
            up[2] = __builtin_bit_cast(unsigned int, __builtin_amdgcn_cvt_pkrtz(pB0, pB1));
            up[3] = __builtin_bit_cast(unsigned int, __builtin_amdgcn_cvt_pkrtz(pB2, pB3));
            f16x8 pa = __builtin_bit_cast(f16x8, up);
#pragma unroll
            for (int c2 = 0; c2 < 4; ++c2) {
                int d = c2 * 16 + l15;
                int nf0a = kkp * 32 + l4 * 4;
                int nf0b = nf0a + 16;
                int rvA = d * 4 + (nf0a >> 6), rvB = d * 4 + (nf0b >> 6);
                int keyA = (rvA ^ (rvA >> 3)) & 7, keyB = (rvB ^ (rvB >> 3)) & 7;
                u32x2 va = *reinterpret_cast<const u32x2*>(
                    Vs + rvA * 64 + ((((nf0a >> 3) & 7) ^ keyA) << 3) + (nf0a & 7));
                u32x2 vb = *reinterpret_cast<const u32x2*>(
                    Vs + rvB * 64 + ((((nf0b >> 3) & 7) ^ keyB) << 3) + (nf0b & 7));
                u32x4 uv; uv[0] = va[0]; uv[1] = va[1]; uv[2] = vb[0]; uv[3] = vb[1];
                f16x8 bv_ = __builtin_bit_cast(f16x8, uv);
                oacc[c2] = __builtin_amdgcn_mfma_f32_16x16x32_f16(pa, bv_, oacc[c2], 0, 0, 0);
            }
            __builtin_amdgcn_sched_barrier(0);
        }
        sum += __shfl_xor(sum, 16, 64);
        sum += __shfl_xor(sum, 32, 64);
        float rs = 1.0f / sum;
        float rsrow[4];
#pragma unroll
        for (int r = 0; r < 4; ++r) rsrow[r] = __shfl(rs, l4 * 4 + r, 64);

#pragma unroll
        for (int c2 = 0; c2 < 4; ++c2)
#pragma unroll
            for (int r = 0; r < 4; ++r) {
                int nf = qrow_base + l4 * 4 + r;
                int dcol = hq + c2 * 16 + l15;
                ao[((size_t)btq + nf) * 512 + dcol] = (f16)(oacc[c2][r] * rsrow[r]);
            }
    }
}

// ---------------- output projection (unchanged) ----------------

__global__ __launch_bounds__(512) void o_gemm(const f16* __restrict__ A, const f16* __restrict__ W,
                                              const float* __restrict__ bo, float* __restrict__ out) {
    __shared__ __align__(16) f16 lds[65536];
    const int tt = threadIdx.x, wave = tt >> 6, lane = tt & 63;
    const int lb = blockIdx.x, xcd = lb & 7, idx = lb >> 3;
    const int m0 = (xcd * 16 + idx / 2) * 256;
    const int n0 = (idx % 2) * 256;
    f32x4 acc[8][4] = {};
    gemm256_core(A, W, m0, n0, lds, acc, wave, lane);

    const int wr = wave & 1, wc = wave >> 1;
    const int l15 = lane & 15, l4 = lane >> 4;
    float bb[4];
#pragma unroll
    for (int bc = 0; bc < 4; ++bc) bb[bc] = bo[n0 + wc * 64 + bc * 16 + l15];
#pragma unroll
    for (int ar = 0; ar < 8; ++ar)
#pragma unroll
        for (int bc = 0; bc < 4; ++bc) {
            int ng = n0 + wc * 64 + bc * 16 + l15;
#pragma unroll
            for (int r = 0; r < 4; ++r) {
                int mg = m0 + wr * 128 + ar * 16 + l4 * 4 + r;
                out[(size_t)mg * 512 + ng] = acc[ar][bc][r] + bb[bc];
            }
        }
}

// ---------------- launch ----------------

extern "C" void kernel_launch(void* const* d_in, const int* in_sizes, int n_in,
                              void* d_out, int out_size, void* d_ws, size_t ws_size,
                              hipStream_t stream) {
    const float* x   = (const float*)d_in[0];
    const int*   adj = (const int*)d_in[1];
    const float* Wq  = (const float*)d_in[2];
    const float* bq  = (const float*)d_in[3];
    const float* Wk  = (const float*)d_in[4];
    const float* bk  = (const float*)d_in[5];
    const float* Wv  = (const float*)d_in[6];
    const float* bv  = (const float*)d_in[7];
    const float* Wo  = (const float*)d_in[8];
    const float* bo  = (const float*)d_in[9];
    float* out = (float*)d_out;

    char* ws = (char*)d_ws;
    f16*   Wh      = (f16*)ws;                                        // 1572864 B
    f16*   Woh     = (f16*)(ws + 1572864);                            //  524288 B
    float* biasAll = (float*)(ws + 2097152);                          //    6144 B
    unsigned long long* bmask = (unsigned long long*)(ws + 2103296);  //    8192 B
    f16*   xh      = (f16*)(ws + 2111488);                            // [M][512] f16 (reused as ao)
    f16*   qkvb    = (f16*)(ws + 2111488 + (size_t)M_ * 512 * 2);     // [M][1024] f16 (q|k)
    f16*   vTb     = (f16*)(ws + 2111488 + (size_t)M_ * 512 * 2 + (size_t)M_ * 1024 * 2); // [128][8][64][256]
    f16*   aob     = xh;

    prep_all<<<2560, 256, 0, stream>>>(x, xh, Wq, Wk, Wv, Wo, bq, bk, bv, adj,
                                       Wh, Woh, biasAll, bmask);
    qkv_gemm<<<768, 512, 0, stream>>>(xh, Wh, biasAll, qkvb, vTb);
    attn_kernel<<<128 * H_, 512, 0, stream>>>(qkvb, vTb, bmask, aob);
    o_gemm<<<256, 512, 0, stream>>>(aob, Woh, bo, out);
}

// Round 13
// 171.229 us; speedup vs baseline: 1.4704x; 1.0224x over previous
//
#include <hip/hip_runtime.h>

#define NF 256
#define H_ 8
#define M_ 32768

typedef _Float16 f16;
typedef _Float16 f16x8 __attribute__((ext_vector_type(8)));
typedef float f32x4 __attribute__((ext_vector_type(4)));
typedef unsigned short u16x8 __attribute__((ext_vector_type(8)));
typedef unsigned int u32x2 __attribute__((ext_vector_type(2)));
typedef unsigned int u32x4 __attribute__((ext_vector_type(4)));

#define GLOAD16(src, dst) \
  __builtin_amdgcn_global_load_lds((const __attribute__((address_space(1))) void*)(src), \
                                   (__attribute__((address_space(3))) void*)(dst), 16, 0, 0)

#define LDS_FENCE() do { asm volatile("s_waitcnt lgkmcnt(0)" ::: "memory"); \
                         __builtin_amdgcn_sched_barrier(0); } while (0)
#define SBAR() asm volatile("s_barrier" ::: "memory")

// ---------------- 256^2 8-phase GEMM core (unchanged from R5) ----------------

__device__ __forceinline__ void stageHT(const f16* __restrict__ g, int r0, int k0,
                                        f16* ldst, int wave, int lane) {
    const int key = lane >> 3;
    const int colsw = k0 + (((lane & 7) ^ key) << 3);
#pragma unroll
    for (int i = 0; i < 2; ++i) {
        int r = i * 64 + wave * 8 + key;
        GLOAD16(g + (size_t)(r0 + r) * 512 + colsw, ldst + (i * 64 + wave * 8) * 64);
    }
}

__device__ __forceinline__ void gemm256_core(const f16* __restrict__ A, const f16* __restrict__ W,
                                             int m0, int n0, f16* lds,
                                             f32x4 (&acc)[8][4], int wave, int lane) {
    const int wr = wave & 1, wc = wave >> 1;
    const int l15 = lane & 15, l4 = lane >> 4;
    stageHT(W, n0,        0, lds + 16384, wave, lane);
    stageHT(W, n0 + 128,  0, lds + 24576, wave, lane);
    stageHT(A, m0,        0, lds,         wave, lane);
    stageHT(A, m0 + 128,  0, lds + 8192,  wave, lane);
    stageHT(W, n0,       64, lds + 32768 + 16384, wave, lane);
    stageHT(W, n0 + 128, 64, lds + 32768 + 24576, wave, lane);
    asm volatile("s_waitcnt vmcnt(4)" ::: "memory");
    SBAR();
#pragma unroll
    for (int t = 0; t < 8; ++t) {
        f16* bufA = lds + (t & 1) * 32768;
        f16* bufB = bufA + 16384;
        f16* nA   = lds + ((t & 1) ^ 1) * 32768;
        f16x8 bfr[4][2];
#pragma unroll
        for (int j = 0; j < 4; ++j)
#pragma unroll
            for (int kk = 0; kk < 2; ++kk) {
                int rb = wc * 64 + j * 16 + l15;
                bfr[j][kk] = *reinterpret_cast<const f16x8*>(
                    bufB + rb * 64 + ((((kk << 2) + l4) ^ (rb & 7)) << 3));
            }
#pragma unroll
        for (int q = 0; q < 4; ++q) {
            f16x8 afr[2][2];
#pragma unroll
            for (int rf = 0; rf < 2; ++rf)
#pragma unroll
                for (int kk = 0; kk < 2; ++kk) {
                    int ra = wr * 128 + q * 32 + rf * 16 + l15;
                    afr[rf][kk] = *reinterpret_cast<const f16x8*>(
                        bufA + ra * 64 + ((((kk << 2) + l4) ^ (ra & 7)) << 3));
                }
            if (q == 0 && t < 7) stageHT(A, m0,       (t + 1) * 64, nA,          wave, lane);
            if (q == 1 && t < 7) stageHT(A, m0 + 128, (t + 1) * 64, nA + 8192,   wave, lane);
            if (q == 2 && t < 6) stageHT(W, n0,       (t + 2) * 64, bufB,        wave, lane);
            if (q == 3 && t < 6) stageHT(W, n0 + 128, (t + 2) * 64, bufB + 8192, wave, lane);
            SBAR();
            LDS_FENCE();
            __builtin_amdgcn_s_setprio(1);
#pragma unroll
            for (int rf = 0; rf < 2; ++rf)
#pragma unroll
                for (int j = 0; j < 4; ++j)
#pragma unroll
                    for (int kk = 0; kk < 2; ++kk)
                        acc[q * 2 + rf][j] = __builtin_amdgcn_mfma_f32_16x16x32_f16(
                            afr[rf][kk], bfr[j][kk], acc[q * 2 + rf][j], 0, 0, 0);
            __builtin_amdgcn_s_setprio(0);
            if (q < 3) SBAR();
        }
        if (t < 6) { asm volatile("s_waitcnt vmcnt(4)" ::: "memory"); }
        else       { asm volatile("s_waitcnt vmcnt(0)" ::: "memory"); }
        SBAR();
    }
}

// ---------------- conversion / prep ----------------

#define QSCALE 0.1803368801111204f   // (1/8) * log2(e)

__global__ void prep_all(const float* __restrict__ x, f16* __restrict__ xh,
                         const float* __restrict__ Wq, const float* __restrict__ Wk,
                         const float* __restrict__ Wv, const float* __restrict__ Wo,
                         const float* __restrict__ bq, const float* __restrict__ bk,
                         const float* __restrict__ bv, const int* __restrict__ adj,
                         f16* __restrict__ Wh, f16* __restrict__ Woh,
                         float* __restrict__ biasAll, unsigned long long* __restrict__ bmask) {
    if (blockIdx.x < 2048) {
        int idx = blockIdx.x * 256 + threadIdx.x;
        for (; idx < M_ * 512 / 8; idx += 2048 * 256) {
            const float4* s = reinterpret_cast<const float4*>(x + (size_t)idx * 8);
            float4 v0 = s[0], v1 = s[1];
            f16x8 o;
            o[0] = (f16)v0.x; o[1] = (f16)v0.y; o[2] = (f16)v0.z; o[3] = (f16)v0.w;
            o[4] = (f16)v1.x; o[5] = (f16)v1.y; o[6] = (f16)v1.z; o[7] = (f16)v1.w;
            *reinterpret_cast<f16x8*>(xh + (size_t)idx * 8) = o;
        }
        return;
    }
    const int tid = (blockIdx.x - 2048) * 256 + threadIdx.x;
    {
        const float* s; f16* d; float sc = 1.0f;
        int pp = tid >> 15, off = tid & 32767;
        if (pp == 0)      { s = Wq; d = Wh;              sc = QSCALE; }
        else if (pp == 1) { s = Wk; d = Wh + 512 * 512; }
        else if (pp == 2) { s = Wv; d = Wh + 2 * 512 * 512; }
        else              { s = Wo; d = Woh; }
        const float4* sv4 = reinterpret_cast<const float4*>(s + (size_t)off * 8);
        float4 v0 = sv4[0], v1 = sv4[1];
        f16x8 o;
        o[0] = (f16)(v0.x * sc); o[1] = (f16)(v0.y * sc);
        o[2] = (f16)(v0.z * sc); o[3] = (f16)(v0.w * sc);
        o[4] = (f16)(v1.x * sc); o[5] = (f16)(v1.y * sc);
        o[6] = (f16)(v1.z * sc); o[7] = (f16)(v1.w * sc);
        *reinterpret_cast<f16x8*>(d + (size_t)off * 8) = o;
    }
    if (tid < 1536) {
        float v = (tid < 512) ? QSCALE * bq[tid] : (tid < 1024) ? bk[tid - 512] : bv[tid - 1024];
        biasAll[tid] = v;
    }
    if (tid < 65536) {
        unsigned long long bal = __ballot(adj[tid] > 0);
        if ((tid & 63) == 0) bmask[tid >> 6] = bal;
    }
}

// ---------------- fused QKV GEMM ----------------
// q,k tiles (n0<1024) -> qkvb [M][1024] row-major via [128][264] epi transpose.
// v tiles (n0>=1024) -> vT via TRANSPOSED epi [256 dk][136 stride] (272 B = 17*16,
// b128-aligned): write side stays 128 scalar ds_write/thread (same as q/k path);
// read side is 8x ds_read_b128 + 8x f16x8 stores (R12's 64 scalar reads cost ~8 us).

__global__ __launch_bounds__(512) void qkv_gemm(const f16* __restrict__ A, const f16* __restrict__ W,
                                                const float* __restrict__ biasAll,
                                                f16* __restrict__ out, f16* __restrict__ vT) {
    __shared__ __align__(16) f16 lds[65536];
    const int tt = threadIdx.x, wave = tt >> 6, lane = tt & 63;
    const int lb = blockIdx.x, xcd = lb & 7, idx = lb >> 3;
    const int m0 = (xcd * 16 + idx / 6) * 256;
    const int n0 = (idx % 6) * 256;
    f32x4 acc[8][4] = {};
    gemm256_core(A, W, m0, n0, lds, acc, wave, lane);

    const int wr = wave & 1, wc = wave >> 1;
    const int l15 = lane & 15, l4 = lane >> 4;
    f16* epi = lds;
    const bool isV = (n0 >= 1024);
    float bb[4];
#pragma unroll
    for (int bc = 0; bc < 4; ++bc) bb[bc] = biasAll[n0 + wc * 64 + bc * 16 + l15];
#pragma unroll
    for (int half = 0; half < 2; ++half) {
        if (wr == half) {
            if (!isV) {
#pragma unroll
                for (int ar = 0; ar < 8; ++ar)
#pragma unroll
                    for (int bc = 0; bc < 4; ++bc)
#pragma unroll
                        for (int r = 0; r < 4; ++r)
                            epi[(ar * 16 + l4 * 4 + r) * 264 + wc * 64 + bc * 16 + l15] =
                                (f16)(acc[ar][bc][r] + bb[bc]);
            } else {
                // transposed: epiT[dk_local = n-col][nf_in_half = m-row], stride 136
#pragma unroll
                for (int ar = 0; ar < 8; ++ar)
#pragma unroll
                    for (int bc = 0; bc < 4; ++bc)
#pragma unroll
                        for (int r = 0; r < 4; ++r)
                            epi[(wc * 64 + bc * 16 + l15) * 136 + ar * 16 + l4 * 4 + r] =
                                (f16)(acc[ar][bc][r] + bb[bc]);
            }
        }
        LDS_FENCE();
        SBAR();
        if (!isV) {
            const int rr = tt >> 5, slot = tt & 31;
#pragma unroll
            for (int p = 0; p < 8; ++p) {
                int row = p * 16 + rr;
                *reinterpret_cast<f16x8*>(out + (size_t)(m0 + half * 128 + row) * 1024 + n0 + slot * 8) =
                    *reinterpret_cast<const f16x8*>(epi + row * 264 + slot * 8);
            }
        } else {
            // vT[(bt*8+h)*64+dk][nf]: vectorized readout of epiT
            f16* vdst = vT + (size_t)(m0 >> 8) * 8 * 64 * 256 + (size_t)(n0 - 1024) * 256;
            const int dk = tt >> 1;
#pragma unroll
            for (int i = 0; i < 8; ++i) {
                int nf0 = (tt & 1) * 64 + i * 8;
                *reinterpret_cast<f16x8*>(vdst + (size_t)dk * 256 + half * 128 + nf0) =
                    *reinterpret_cast<const f16x8*>(epi + dk * 136 + nf0);
            }
        }
        SBAR();
    }
}

// ---------------- attention (swapped QK^T, fused per-kkp drain+PV — unchanged R12) ----------------

template <int NR>
__device__ __forceinline__ void stage_rows512(const f16* __restrict__ g, int ld, int coff,
                                              f16* ldsb, int wave, int lane) {
    const int rr = wave * 8 + (lane >> 3);
    const int p  = lane & 7;
#pragma unroll
    for (int i = 0; i < NR / 64; ++i) {
        int r = i * 64 + rr;
        int col = ((p ^ (r & 7)) << 3);
        GLOAD16(g + (size_t)r * ld + coff + col, ldsb + (i * 64 + wave * 8) * 64);
    }
}

// V^T panel [64 dk][256 nf] viewed as 256 rows (rv = dk*4+chunk) of 64 f16,
// swizzle key = (rv ^ (rv>>3)) & 7 on the 16B slot.
__device__ __forceinline__ void stage_v512(const f16* __restrict__ g, f16* ldsb,
                                           int wave, int lane) {
    const int rr = wave * 8 + (lane >> 3);
    const int p  = lane & 7;
#pragma unroll
    for (int i = 0; i < 4; ++i) {
        int r = i * 64 + rr;
        int key = (r ^ (r >> 3)) & 7;
        GLOAD16(g + (size_t)r * 64 + ((p ^ key) << 3), ldsb + (i * 64 + wave * 8) * 64);
    }
}

__global__ __launch_bounds__(512, 2) void attn_kernel(const f16* __restrict__ qkv,
                                                      const f16* __restrict__ vT,
                                                      const unsigned long long* __restrict__ bmg,
                                                      f16* __restrict__ ao) {
    __shared__ f16 Ks[256 * 64];
    __shared__ f16 Vs[256 * 64];
    __shared__ unsigned long long BMs[1024];
    const int t = threadIdx.x, wave = t >> 6, lane = t & 63;
    const int l15 = lane & 15, l4 = lane >> 4;
    const int bh = blockIdx.x, bt = bh >> 3, h = bh & 7;
    const int btq = bt * 256, hq = h * 64;
    const f16* qb = qkv + (size_t)btq * 1024 + hq;
    const f16* kb = qb + 512;

    stage_rows512<256>(kb, 1024, 0, Ks, wave, lane);
    stage_v512(vT + (size_t)bh * 16384, Vs, wave, lane);
    GLOAD16((const char*)bmg + (size_t)t * 16, (char*)(BMs + wave * 128));
    __syncthreads();

    for (int s = 0; s < 2; ++s) {
        const int qrow_base = wave * 32 + s * 16;

        f16x8 aq[2];
#pragma unroll
        for (int kk = 0; kk < 2; ++kk)
            aq[kk] = *reinterpret_cast<const f16x8*>(
                qb + (size_t)(qrow_base + l15) * 1024 + kk * 32 + l4 * 8);

        // S^T = K·Q^T : lane holds S[k = ct*16 + l4*4 + r][q = qrow_base + l15]
        f32x4 sc[16];
#pragma unroll
        for (int ct = 0; ct < 16; ++ct) sc[ct] = (f32x4){0.f, 0.f, 0.f, 0.f};
#pragma unroll
        for (int ct = 0; ct < 16; ++ct)
#pragma unroll
            for (int kk = 0; kk < 2; ++kk) {
                int rk = ct * 16 + l15;
                int sk = kk * 4 + l4;
                f16x8 bk_ = *reinterpret_cast<const f16x8*>(Ks + rk * 64 + ((sk ^ (rk & 7)) << 3));
                sc[ct] = __builtin_amdgcn_mfma_f32_16x16x32_f16(bk_, aq[kk], sc[ct], 0, 0, 0);
            }

        // max over raw 64 k-values in-lane + 2 shuffles (shift-invariance: mask later)
        float mx = -1e38f;
#pragma unroll
        for (int ct = 0; ct < 16; ++ct)
#pragma unroll
            for (int r = 0; r < 4; ++r) mx = fmaxf(mx, sc[ct][r]);
        mx = fmaxf(mx, __shfl_xor(mx, 16, 64));
        mx = fmaxf(mx, __shfl_xor(mx, 32, 64));

        const int ig = qrow_base + l15;
        const u16x8* mr = reinterpret_cast<const u16x8*>(BMs + ig * 4);
        u16x8 w0 = mr[0], w1 = mr[1];

        // fused drain + PV: per kkp, consume sc pair -> pack pa -> 4 MFMAs.
        // sched_barrier(0) bounds the scheduler's live window to one iteration.
        f32x4 oacc[4] = {};
        float sum = 0.f;
#pragma unroll
        for (int kkp = 0; kkp < 8; ++kkp) {
            const int ctA = 2 * kkp, ctB = 2 * kkp + 1;
            unsigned mbA = ((kkp < 4) ? (unsigned)w0[ctA] : (unsigned)w1[ctA & 7]) >> (l4 * 4);
            unsigned mbB = ((kkp < 4) ? (unsigned)w0[ctB] : (unsigned)w1[ctB & 7]) >> (l4 * 4);
            float pA0 = __builtin_exp2f(sc[ctA][0] - mx); pA0 = ((mbA >> 0) & 1u) ? pA0 : 0.0f;
            float pA1 = __builtin_exp2f(sc[ctA][1] - mx); pA1 = ((mbA >> 1) & 1u) ? pA1 : 0.0f;
            float pA2 = __builtin_exp2f(sc[ctA][2] - mx); pA2 = ((mbA >> 2) & 1u) ? pA2 : 0.0f;
            float pA3 = __builtin_exp2f(sc[ctA][3] - mx); pA3 = ((mbA >> 3) & 1u) ? pA3 : 0.0f;
            float pB0 = __builtin_exp2f(sc[ctB][0] - mx); pB0 = ((mbB >> 0) & 1u) ? pB0 : 0.0f;
            float pB1 = __builtin_exp2f(sc[ctB][1] - mx); pB1 = ((mbB >> 1) & 1u) ? pB1 : 0.0f;
            float pB2 = __builtin_exp2f(sc[ctB][2] - mx); pB2 = ((mbB >> 2) & 1u) ? pB2 : 0.0f;
            float pB3 = __builtin_exp2f(sc[ctB][3] - mx); pB3 = ((mbB >> 3) & 1u) ? pB3 : 0.0f;
            sum += (pA0 + pA1) + (pA2 + pA3) + (pB0 + pB1) + (pB2 + pB3);
            u32x4 up;
            up[0] = __builtin_bit_cast(unsigned int, __builtin_amdgcn_cvt_pkrtz(pA0, pA1));
            up[1] = __builtin_bit_cast(unsigned int, __builtin_amdgcn_cvt_pkrtz(pA2, pA3));
            up[2] = __builtin_bit_cast(unsigned int, __builtin_amdgcn_cvt_pkrtz(pB0, pB1));
            up[3] = __builtin_bit_cast(unsigned int, __builtin_amdgcn_cvt_pkrtz(pB2, pB3));
            f16x8 pa = __builtin_bit_cast(f16x8, up);
#pragma unroll
            for (int c2 = 0; c2 < 4; ++c2) {
                int d = c2 * 16 + l15;
                int nf0a = kkp * 32 + l4 * 4;
                int nf0b = nf0a + 16;
                int rvA = d * 4 + (nf0a >> 6), rvB = d * 4 + (nf0b >> 6);
                int keyA = (rvA ^ (rvA >> 3)) & 7, keyB = (rvB ^ (rvB >> 3)) & 7;
                u32x2 va = *reinterpret_cast<const u32x2*>(
                    Vs + rvA * 64 + ((((nf0a >> 3) & 7) ^ keyA) << 3) + (nf0a & 7));
                u32x2 vb = *reinterpret_cast<const u32x2*>(
                    Vs + rvB * 64 + ((((nf0b >> 3) & 7) ^ keyB) << 3) + (nf0b & 7));
                u32x4 uv; uv[0] = va[0]; uv[1] = va[1]; uv[2] = vb[0]; uv[3] = vb[1];
                f16x8 bv_ = __builtin_bit_cast(f16x8, uv);
                oacc[c2] = __builtin_amdgcn_mfma_f32_16x16x32_f16(pa, bv_, oacc[c2], 0, 0, 0);
            }
            __builtin_amdgcn_sched_barrier(0);
        }
        sum += __shfl_xor(sum, 16, 64);
        sum += __shfl_xor(sum, 32, 64);
        float rs = 1.0f / sum;
        float rsrow[4];
#pragma unroll
        for (int r = 0; r < 4; ++r) rsrow[r] = __shfl(rs, l4 * 4 + r, 64);

#pragma unroll
        for (int c2 = 0; c2 < 4; ++c2)
#pragma unroll
            for (int r = 0; r < 4; ++r) {
                int nf = qrow_base + l4 * 4 + r;
                int dcol = hq + c2 * 16 + l15;
                ao[((size_t)btq + nf) * 512 + dcol] = (f16)(oacc[c2][r] * rsrow[r]);
            }
    }
}

// ---------------- output projection (unchanged) ----------------

__global__ __launch_bounds__(512) void o_gemm(const f16* __restrict__ A, const f16* __restrict__ W,
                                              const float* __restrict__ bo, float* __restrict__ out) {
    __shared__ __align__(16) f16 lds[65536];
    const int tt = threadIdx.x, wave = tt >> 6, lane = tt & 63;
    const int lb = blockIdx.x, xcd = lb & 7, idx = lb >> 3;
    const int m0 = (xcd * 16 + idx / 2) * 256;
    const int n0 = (idx % 2) * 256;
    f32x4 acc[8][4] = {};
    gemm256_core(A, W, m0, n0, lds, acc, wave, lane);

    const int wr = wave & 1, wc = wave >> 1;
    const int l15 = lane & 15, l4 = lane >> 4;
    float bb[4];
#pragma unroll
    for (int bc = 0; bc < 4; ++bc) bb[bc] = bo[n0 + wc * 64 + bc * 16 + l15];
#pragma unroll
    for (int ar = 0; ar < 8; ++ar)
#pragma unroll
        for (int bc = 0; bc < 4; ++bc) {
            int ng = n0 + wc * 64 + bc * 16 + l15;
#pragma unroll
            for (int r = 0; r < 4; ++r) {
                int mg = m0 + wr * 128 + ar * 16 + l4 * 4 + r;
                out[(size_t)mg * 512 + ng] = acc[ar][bc][r] + bb[bc];
            }
        }
}

// ---------------- launch ----------------

extern "C" void kernel_launch(void* const* d_in, const int* in_sizes, int n_in,
                              void* d_out, int out_size, void* d_ws, size_t ws_size,
                              hipStream_t stream) {
    const float* x   = (const float*)d_in[0];
    const int*   adj = (const int*)d_in[1];
    const float* Wq  = (const float*)d_in[2];
    const float* bq  = (const float*)d_in[3];
    const float* Wk  = (const float*)d_in[4];
    const float* bk  = (const float*)d_in[5];
    const float* Wv  = (const float*)d_in[6];
    const float* bv  = (const float*)d_in[7];
    const float* Wo  = (const float*)d_in[8];
    const float* bo  = (const float*)d_in[9];
    float* out = (float*)d_out;

    char* ws = (char*)d_ws;
    f16*   Wh      = (f16*)ws;                                        // 1572864 B
    f16*   Woh     = (f16*)(ws + 1572864);                            //  524288 B
    float* biasAll = (float*)(ws + 2097152);                          //    6144 B
    unsigned long long* bmask = (unsigned long long*)(ws + 2103296);  //    8192 B
    f16*   xh      = (f16*)(ws + 2111488);                            // [M][512] f16 (reused as ao)
    f16*   qkvb    = (f16*)(ws + 2111488 + (size_t)M_ * 512 * 2);     // [M][1024] f16 (q|k)
    f16*   vTb     = (f16*)(ws + 2111488 + (size_t)M_ * 512 * 2 + (size_t)M_ * 1024 * 2); // [128][8][64][256]
    f16*   aob     = xh;

    prep_all<<<2560, 256, 0, stream>>>(x, xh, Wq, Wk, Wv, Wo, bq, bk, bv, adj,
                                       Wh, Woh, biasAll, bmask);
    qkv_gemm<<<768, 512, 0, stream>>>(xh, Wh, biasAll, qkvb, vTb);
    attn_kernel<<<128 * H_, 512, 0, stream>>>(qkvb, vTb, bmask, aob);
    o_gemm<<<256, 512, 0, stream>>>(aob, Woh, bo, out);
}